// Round 8
// baseline (5625.356 us; speedup 1.0000x reference)
//
#include <hip/hip_runtime.h>
#include <hip/hip_bf16.h>

#define NN 50000
#define NE 1000000
#define CC 64
#define LL 16
#define KSEL 512
#define HIDD 1024
#define FULLW 1152
#define EPSV 1e-5f
#define NTILE 4
#define TROWS 12800
#define RPN (4 * NN)
#define SBLK 196  // ceil(RPN / 1024)

typedef float f4v __attribute__((ext_vector_type(4)));

__device__ inline float4 nt_load4(const float* p) {
  f4v v = __builtin_nontemporal_load((const f4v*)p);
  return make_float4(v.x, v.y, v.z, v.w);
}
__device__ inline void nt_store4(float* p, float a, float b, float c, float d) {
  f4v v = {a, b, c, d};
  __builtin_nontemporal_store(v, (f4v*)p);
}

// ---------------- CSR build (keyed by (node, src-tile)) ----------------

__global__ __launch_bounds__(256) void hist_kernel(const int* __restrict__ src,
    const int* __restrict__ dst, int* __restrict__ cnt_in, int* __restrict__ cnt_out) {
  int stride = gridDim.x * blockDim.x;
  for (int e = blockIdx.x * blockDim.x + threadIdx.x; e < NE; e += stride) {
    int s = src[e], d = dst[e];
    atomicAdd(&cnt_in[d * NTILE + s / TROWS], 1);
    atomicAdd(&cnt_out[s * NTILE + d / TROWS], 1);
  }
}

// hierarchical scan: scan1 (per-1024-block exclusive) -> scan2 (block totals) ->
// scan3 (apply offsets + build rp + init cur + zero statsA)

__global__ __launch_bounds__(1024) void scan1_kernel(const int* __restrict__ cnt,
    int* __restrict__ rptmp, int* __restrict__ btot) {
  int a = blockIdx.x / SBLK, blk = blockIdx.x % SBLK;
  int t = threadIdx.x;
  int idx = blk * 1024 + t;
  int v = (idx < RPN) ? cnt[a * RPN + idx] : 0;
  __shared__ int sm[1024];
  sm[t] = v;
  __syncthreads();
  for (int off = 1; off < 1024; off <<= 1) {
    int u = (t >= off) ? sm[t - off] : 0;
    __syncthreads();
    sm[t] += u;
    __syncthreads();
  }
  int incl = sm[t];
  if (idx < RPN) rptmp[a * RPN + idx] = incl - v;
  if (t == 1023) btot[a * SBLK + blk] = incl;
}

__global__ __launch_bounds__(256) void scan2_kernel(int* __restrict__ btot) {
  __shared__ int sm[256];
  int t = threadIdx.x;
  for (int a = 0; a < 2; ++a) {
    int v = (t < SBLK) ? btot[a * SBLK + t] : 0;
    sm[t] = v;
    __syncthreads();
    for (int off = 1; off < 256; off <<= 1) {
      int u = (t >= off) ? sm[t - off] : 0;
      __syncthreads();
      sm[t] += u;
      __syncthreads();
    }
    if (t < SBLK) btot[a * SBLK + t] = sm[t] - v;
    __syncthreads();
  }
}

__global__ __launch_bounds__(256) void scan3_kernel(const int* __restrict__ rptmp,
    const int* __restrict__ btot, int* __restrict__ rp, int* __restrict__ cur,
    float* __restrict__ statsA) {
  int gid = blockIdx.x * 256 + threadIdx.x;
  if (gid < 2 * RPN) {
    int a = gid / RPN, idx = gid - a * RPN;
    int v = rptmp[gid] + btot[a * SBLK + (idx >> 10)];
    rp[a * (RPN + 1) + idx] = v;
    cur[gid] = v;
    if (idx == 0) rp[a * (RPN + 1) + RPN] = NE;
  }
  if (gid < 128) statsA[gid] = 0.f;
}

__global__ __launch_bounds__(256) void fill_kernel(const int* __restrict__ src,
    const int* __restrict__ dst, int* __restrict__ cur_in, int* __restrict__ cur_out,
    int* __restrict__ col_in, int* __restrict__ col_out) {
  int stride = gridDim.x * blockDim.x;
  for (int e = blockIdx.x * blockDim.x + threadIdx.x; e < NE; e += stride) {
    int s = src[e], d = dst[e];
    int p = atomicAdd(&cur_in[d * NTILE + s / TROWS], 1);
    col_in[p] = s;
    int q = atomicAdd(&cur_out[s * NTILE + d / TROWS], 1);
    col_out[q] = d;
  }
}

// ---------------- embedding + sel gather ----------------

__global__ __launch_bounds__(256) void embed_kernel(const int* __restrict__ nt,
    const float* __restrict__ emb, float* __restrict__ X) {
  int id = blockIdx.x * 256 + threadIdx.x;
  if (id >= NN * CC) return;
  X[id] = emb[nt[id >> 6] * CC + (id & 63)];
}

__global__ __launch_bounds__(256) void gather_sel_kernel(const float* __restrict__ xsrc,
    const int* __restrict__ idx, float* __restrict__ sel, int coloff) {
  int tid = blockIdx.x * 256 + threadIdx.x;
  if (tid >= KSEL * CC) return;
  int k = tid >> 6, cch = tid & 63;
  sel[k * FULLW + coloff + cch] = xsrc[idx[k] * CC + cch];
}

// ---------------- matmul: Y = f(X) @ W ----------------

__global__ __launch_bounds__(256) void mm_kernel(const float* __restrict__ X,
    float* __restrict__ Y, const float* __restrict__ W,
    const float* __restrict__ stats, const float* __restrict__ gamma,
    const float* __restrict__ beta, float* __restrict__ stats_zero) {
  int t = threadIdx.x;
  int lane = t & 63;
  int wid = t >> 6;
  float wreg[CC];
  {
    const float* wb = W + (lane >> 5) * 2048 + (lane & 31);
#pragma unroll
    for (int c2 = 0; c2 < CC; ++c2) wreg[c2] = wb[c2 * 32];
  }
  __shared__ float sc[CC], sh[CC];
  __shared__ __align__(16) float Xs[64][CC];
  if (t < CC) {
    float scale = 1.f, shift = 0.f;
    if (stats) {
      float m = stats[t] * (1.f / NN);
      float v = stats[CC + t] * (1.f / NN) - m * m;
      float is = rsqrtf(v + EPSV);
      scale = gamma[t] * is;
      shift = beta[t] - m * scale;
    }
    sc[t] = scale; sh[t] = shift;
  }
  if (stats_zero && blockIdx.x == 0 && t < 128) stats_zero[t] = 0.f;
  const bool bn = (stats != nullptr);
  for (int row0 = blockIdx.x * 64; row0 < NN; row0 += gridDim.x * 64) {
    int nrows = min(64, NN - row0);
    __syncthreads();
    for (int idx = t; idx < nrows * 16; idx += 256) {
      int r = idx >> 4, cq = idx & 15;
      float4 v = *(const float4*)(X + (size_t)(row0 + r) * CC + cq * 4);
      if (bn) {
        int c0 = cq * 4;
        v.x = fmaxf(v.x, 0.f) * sc[c0]     + sh[c0];
        v.y = fmaxf(v.y, 0.f) * sc[c0 + 1] + sh[c0 + 1];
        v.z = fmaxf(v.z, 0.f) * sc[c0 + 2] + sh[c0 + 2];
        v.w = fmaxf(v.w, 0.f) * sc[c0 + 3] + sh[c0 + 3];
      }
      *(float4*)&Xs[r][cq * 4] = v;
    }
    __syncthreads();
    for (int r = wid; r < nrows; r += 4) {
      const float* xr = &Xs[r][0];
      float a0 = 0.f, a1 = 0.f, a2 = 0.f, a3 = 0.f;
#pragma unroll
      for (int c2 = 0; c2 < CC; c2 += 4) {
        float4 xv = *(const float4*)(xr + c2);
        a0 += xv.x * wreg[c2];
        a1 += xv.y * wreg[c2 + 1];
        a2 += xv.z * wreg[c2 + 2];
        a3 += xv.w * wreg[c2 + 3];
      }
      Y[(size_t)(row0 + r) * CC + lane] = (a0 + a1) + (a2 + a3);
    }
  }
}

// ---------------- segment-sum, ONE TILE PER LAUNCH (L2-resident window) ----------------
// tile pass p gathers only Y rows in [p*TROWS,(p+1)*TROWS) (~3.3MB, fits per-XCD L2).
// Kernel boundary enforces lockstep. Streams (col/rp/OUT/skip) use non-temporal
// ops so they don't evict the Y tile. Pass 0 folds skip; passes >0 rmw OUT;
// stats taken in the last pass. Lane: d=bit5, s=bits3..4 (slot), cb=bits0..2.

__global__ __launch_bounds__(256) void seg_kernel(
    const float* __restrict__ Y, const float* skip, float* OUT,
    const int* __restrict__ rp_in, const int* __restrict__ col_in,
    const int* __restrict__ rp_out, const int* __restrict__ col_out,
    float* __restrict__ stats_acc, int tile) {
  int t = threadIdx.x;
  int w = t >> 6;
  int d = (t >> 5) & 1;
  int l31 = t & 31;
  int s = l31 >> 3;
  int cb = l31 & 7;
  const int* rp = d ? rp_out : rp_in;
  const int* col = d ? col_out : col_in;
  const bool first = (tile == 0);
  const bool last = (tile == NTILE - 1);
  float s1[4], s2[4];
#pragma unroll
  for (int k = 0; k < 4; ++k) { s1[k] = 0.f; s2[k] = 0.f; }

  for (int i = blockIdx.x * 4 + w; i < NN; i += gridDim.x * 4) {
    int rbase = (i << 2) | tile;
    int beg = __builtin_nontemporal_load(&rp[rbase]);
    int deg = __builtin_nontemporal_load(&rp[rbase + 1]) - beg;
    // phase 1: slot-chain index loads (covers deg<=8 per direction)
    int idx[2];
#pragma unroll
    for (int b = 0; b < 2; ++b) {
      int e = s + b * 4;
      idx[b] = (e < deg) ? __builtin_nontemporal_load(&col[beg + e]) : -1;
    }
    // phase 2: independent gathers (Y stays cached - normal loads)
    float acc0[4] = {0.f, 0.f, 0.f, 0.f};
    float acc1[4] = {0.f, 0.f, 0.f, 0.f};
#pragma unroll
    for (int b = 0; b < 2; ++b) {
      if (idx[b] >= 0) {
        float4 v = *(const float4*)(Y + (((size_t)idx[b]) << 6) + (d << 5) + (cb << 2));
        float* a = b ? acc1 : acc0;
        a[0] += v.x; a[1] += v.y; a[2] += v.z; a[3] += v.w;
      }
    }
    // tail: deg > 8 within this tile (~7% of buckets)
    for (int e = s + 8; e < deg; e += 4) {
      int j = __builtin_nontemporal_load(&col[beg + e]);
      float4 v = *(const float4*)(Y + (((size_t)j) << 6) + (d << 5) + (cb << 2));
      acc1[0] += v.x; acc1[1] += v.y; acc1[2] += v.z; acc1[3] += v.w;
    }
    float acc[4];
#pragma unroll
    for (int k = 0; k < 4; ++k) acc[k] = acc0[k] + acc1[k];
#pragma unroll
    for (int m = 8; m <= 16; m <<= 1) {
#pragma unroll
      for (int k = 0; k < 4; ++k) acc[k] += __shfl_xor(acc[k], m, 64);
    }
    if (s == 0) {
      size_t obase = (size_t)i * CC + d * 32 + cb * 4;
      if (first) {
        if (skip) {
          float4 k0 = nt_load4(skip + obase);
          acc[0] += k0.x; acc[1] += k0.y; acc[2] += k0.z; acc[3] += k0.w;
        }
      } else {
        float4 k0 = nt_load4(OUT + obase);
        acc[0] += k0.x; acc[1] += k0.y; acc[2] += k0.z; acc[3] += k0.w;
      }
      nt_store4(OUT + obase, acc[0], acc[1], acc[2], acc[3]);
      if (last && stats_acc) {
#pragma unroll
        for (int k = 0; k < 4; ++k) {
          float r = fmaxf(acc[k], 0.f);
          s1[k] += r; s2[k] += r * r;
        }
      }
    }
  }
  if (last && stats_acc) {
    __shared__ float red1[256], red2[256];
    if (s == 0) {
      int q = ((w * 2 + d) * 8 + cb) * 4;
#pragma unroll
      for (int k = 0; k < 4; ++k) { red1[q + k] = s1[k]; red2[q + k] = s2[k]; }
    }
    __syncthreads();
    if (t < 64) {
      int dd = t >> 5, cc = (t >> 2) & 7, k = t & 3;
      float v1 = 0.f, v2 = 0.f;
#pragma unroll
      for (int ww = 0; ww < 4; ++ww) {
        int q = ((ww * 2 + dd) * 8 + cc) * 4 + k;
        v1 += red1[q]; v2 += red2[q];
      }
      atomicAdd(&stats_acc[t], v1);
      atomicAdd(&stats_acc[CC + t], v2);
    }
  }
}

// ---------------- head ----------------

__global__ __launch_bounds__(256) void hidden_kernel(const float* __restrict__ sel,
    const float* __restrict__ Wh, const float* __restrict__ bh, float* __restrict__ h1) {
  int t = threadIdx.x;
  int lane = t & 63, w = t >> 6;
  int jb = blockIdx.x & 15;
  int rbg = blockIdx.x >> 4;
  int j = jb * 64 + lane;
  int r0 = rbg * 16;
  __shared__ __align__(16) float Ws[64][64];
  __shared__ __align__(16) float Ss[16][64];
  float acc[4] = {0.f, 0.f, 0.f, 0.f};
  for (int k0 = 0; k0 < FULLW; k0 += 64) {
    __syncthreads();
    {
      int col = (t & 15) * 4;
      int kk = t >> 4;
#pragma unroll
      for (int p = 0; p < 4; ++p) {
        float4 v = *(const float4*)(Wh + (size_t)(k0 + kk + p * 16) * HIDD + jb * 64 + col);
        *(float4*)&Ws[kk + p * 16][col] = v;
      }
      float4 v = *(const float4*)(sel + (size_t)(r0 + kk) * FULLW + k0 + col);
      v.x = fmaxf(v.x, 0.f); v.y = fmaxf(v.y, 0.f);
      v.z = fmaxf(v.z, 0.f); v.w = fmaxf(v.w, 0.f);
      *(float4*)&Ss[kk][col] = v;
    }
    __syncthreads();
    float wreg[64];
#pragma unroll
    for (int kk = 0; kk < 64; ++kk) wreg[kk] = Ws[kk][lane];
#pragma unroll
    for (int rr = 0; rr < 4; ++rr) {
      const float4* sr = (const float4*)&Ss[w * 4 + rr][0];
      float a0 = 0.f, a1 = 0.f, a2 = 0.f, a3 = 0.f;
#pragma unroll
      for (int kq = 0; kq < 16; ++kq) {
        float4 sv = sr[kq];
        a0 += sv.x * wreg[kq * 4];
        a1 += sv.y * wreg[kq * 4 + 1];
        a2 += sv.z * wreg[kq * 4 + 2];
        a3 += sv.w * wreg[kq * 4 + 3];
      }
      acc[rr] += (a0 + a1) + (a2 + a3);
    }
  }
#pragma unroll
  for (int rr = 0; rr < 4; ++rr)
    h1[(size_t)(r0 + w * 4 + rr) * HIDD + j] = acc[rr] + bh[j];
}

__global__ __launch_bounds__(256) void out_kernel(const float* __restrict__ h1,
    const float* __restrict__ ow, const float* __restrict__ ob, float* __restrict__ logits) {
  int k = blockIdx.x * 4 + (threadIdx.x >> 6);
  int lane = threadIdx.x & 63;
  if (k >= KSEL) return;
  float a = 0.f;
  for (int j = lane; j < HIDD; j += 64) {
    float v = h1[k * HIDD + j];
    a += fmaxf(v, 0.f) * ow[j];
  }
  for (int off = 32; off; off >>= 1) a += __shfl_down(a, off, 64);
  if (lane == 0) logits[k] = a + ob[0];
}

__global__ __launch_bounds__(512) void softmax_kernel(const float* __restrict__ logits,
    float* __restrict__ out) {
  int t = threadIdx.x;
  float v = logits[t];
  __shared__ float red[512];
  red[t] = v;
  __syncthreads();
  for (int s = 256; s; s >>= 1) { if (t < s) red[t] = fmaxf(red[t], red[t + s]); __syncthreads(); }
  float mx = red[0];
  __syncthreads();
  float e = expf(v - mx);
  red[t] = e;
  __syncthreads();
  for (int s = 256; s; s >>= 1) { if (t < s) red[t] += red[t + s]; __syncthreads(); }
  out[t] = e / red[0];
}

// ---------------- launch ----------------

extern "C" void kernel_launch(void* const* d_in, const int* in_sizes, int n_in,
                              void* d_out, int out_size, void* d_ws, size_t ws_size,
                              hipStream_t stream) {
  const int* node_types = (const int*)d_in[0];
  const int* edge_index = (const int*)d_in[1];
  const int* indices = (const int*)d_in[2];
  const float* emb = (const float*)d_in[3];
  const float* conv0_w = (const float*)d_in[4];
  const float* bn_g = (const float*)d_in[5];
  const float* bn_b = (const float*)d_in[6];
  const float* res_w = (const float*)d_in[7];
  const float* hw = (const float*)d_in[8];
  const float* hb = (const float*)d_in[9];
  const float* ow = (const float*)d_in[10];
  const float* ob = (const float*)d_in[11];
  float* out = (float*)d_out;
  const int* src = edge_index;
  const int* dst = edge_index + NE;

  char* p = (char*)d_ws;
  size_t off = 0;
  auto alloc = [&](size_t bytes) -> void* {
    void* q = p + off;
    off += (bytes + 255) & ~(size_t)255;
    return q;
  };
  int* cnt = (int*)alloc(2 * RPN * sizeof(int));        // cnt_in | cnt_out
  int* rptmp = (int*)alloc(2 * RPN * sizeof(int));
  int* btot = (int*)alloc(2 * SBLK * sizeof(int));
  int* rp = (int*)alloc(2 * (RPN + 1) * sizeof(int));   // rp_in | rp_out
  int* cur = (int*)alloc(2 * RPN * sizeof(int));
  int* col_in = (int*)alloc((size_t)NE * sizeof(int));
  int* col_out = (int*)alloc((size_t)NE * sizeof(int));
  float* X = (float*)alloc((size_t)NN * CC * 4);
  float* H = (float*)alloc((size_t)NN * CC * 4);
  float* Y = (float*)alloc((size_t)NN * CC * 4);
  float* statsA = (float*)alloc(128 * 4);
  float* statsB = (float*)alloc(128 * 4);
  float* sel = (float*)alloc((size_t)KSEL * FULLW * 4);
  float* h1 = (float*)alloc((size_t)KSEL * HIDD * 4);
  float* logits = (float*)alloc(KSEL * 4);
  (void)ws_size; (void)in_sizes; (void)n_in; (void)out_size;

  int* cnt_in = cnt;  int* cnt_out = cnt + RPN;
  int* rp_in = rp;    int* rp_out = rp + RPN + 1;
  int* cur_in = cur;  int* cur_out = cur + RPN;

  hipMemsetAsync(cnt, 0, 2 * RPN * sizeof(int), stream);
  hipLaunchKernelGGL(hist_kernel, dim3(1024), dim3(256), 0, stream, src, dst, cnt_in, cnt_out);
  hipLaunchKernelGGL(scan1_kernel, dim3(2 * SBLK), dim3(1024), 0, stream, cnt, rptmp, btot);
  hipLaunchKernelGGL(scan2_kernel, dim3(1), dim3(256), 0, stream, btot);
  hipLaunchKernelGGL(scan3_kernel, dim3((2 * RPN + 255) / 256), dim3(256), 0, stream,
                     rptmp, btot, rp, cur, statsA);
  // note: scan3 writes rp as [in | out] with rp_in = rp, rp_out = rp + RPN + 1
  hipLaunchKernelGGL(fill_kernel, dim3(1024), dim3(256), 0, stream, src, dst,
                     cur_in, cur_out, col_in, col_out);

  hipLaunchKernelGGL(embed_kernel, dim3((NN * CC + 255) / 256), dim3(256), 0, stream,
                     node_types, emb, X);
  hipLaunchKernelGGL(gather_sel_kernel, dim3(KSEL * CC / 256), dim3(256), 0, stream,
                     X, indices, sel, 0);

  auto seg4 = [&](const float* Yb, const float* skipb, float* OUTb, float* statsb) {
    for (int tl = 0; tl < NTILE; ++tl)
      hipLaunchKernelGGL(seg_kernel, dim3(2048), dim3(256), 0, stream, Yb, skipb, OUTb,
                         rp_in, col_in, rp_out, col_out, statsb, tl);
  };

  // conv0 (no BN); accumulate relu stats of its output into statsA
  hipLaunchKernelGGL(mm_kernel, dim3(782), dim3(256), 0, stream, X, Y, conv0_w,
                     (const float*)nullptr, (const float*)nullptr, (const float*)nullptr,
                     (float*)nullptr);
  seg4(Y, nullptr, X, statsA);
  hipLaunchKernelGGL(gather_sel_kernel, dim3(KSEL * CC / 256), dim3(256), 0, stream,
                     X, indices, sel, CC);

  for (int l = 0; l < LL; ++l) {
    const float* w1 = res_w + (size_t)(l * 2 + 0) * 4096;
    const float* w2 = res_w + (size_t)(l * 2 + 1) * 4096;
    const float* g1 = bn_g + (l * 2 + 0) * CC;
    const float* b1 = bn_b + (l * 2 + 0) * CC;
    const float* g2 = bn_g + (l * 2 + 1) * CC;
    const float* b2 = bn_b + (l * 2 + 1) * CC;
    hipLaunchKernelGGL(mm_kernel, dim3(782), dim3(256), 0, stream, X, Y, w1, statsA, g1, b1, statsB);
    seg4(Y, nullptr, H, statsB);
    hipLaunchKernelGGL(mm_kernel, dim3(782), dim3(256), 0, stream, H, Y, w2, statsB, g2, b2, statsA);
    seg4(Y, X, X, statsA);
    hipLaunchKernelGGL(gather_sel_kernel, dim3(KSEL * CC / 256), dim3(256), 0, stream,
                       X, indices, sel, 2 * CC + l * CC);
  }

  hipLaunchKernelGGL(hidden_kernel, dim3(512), dim3(256), 0, stream, sel, hw, hb, h1);
  hipLaunchKernelGGL(out_kernel, dim3(KSEL / 4), dim3(256), 0, stream, h1, ow, ob, logits);
  hipLaunchKernelGGL(softmax_kernel, dim3(1), dim3(512), 0, stream, logits, out);
}

// Round 9
// 3677.119 us; speedup vs baseline: 1.5298x; 1.5298x over previous
//
#include <hip/hip_runtime.h>
#include <hip/hip_bf16.h>

#define NN 50000
#define NE 1000000
#define CC 64
#define LL 16
#define KSEL 512
#define HIDD 1024
#define FULLW 1152
#define EPSV 1e-5f
#define SBLK 49  // ceil(NN / 1024)

// ---------------- CSR build ----------------

__global__ __launch_bounds__(256) void hist_kernel(const int* __restrict__ src,
    const int* __restrict__ dst, int* __restrict__ cnt_in, int* __restrict__ cnt_out) {
  int stride = gridDim.x * blockDim.x;
  for (int e = blockIdx.x * blockDim.x + threadIdx.x; e < NE; e += stride) {
    atomicAdd(&cnt_in[dst[e]], 1);
    atomicAdd(&cnt_out[src[e]], 1);
  }
}

// hierarchical scan: scan1 (per-1024-block) -> scan2 (block totals) ->
// scan3 (apply offsets + build rp + init cur + zero statsA)

__global__ __launch_bounds__(1024) void scan1_kernel(const int* __restrict__ cnt,
    int* __restrict__ rptmp, int* __restrict__ btot) {
  int a = blockIdx.x / SBLK, blk = blockIdx.x % SBLK;
  int t = threadIdx.x;
  int idx = blk * 1024 + t;
  int v = (idx < NN) ? cnt[a * NN + idx] : 0;
  __shared__ int sm[1024];
  sm[t] = v;
  __syncthreads();
  for (int off = 1; off < 1024; off <<= 1) {
    int u = (t >= off) ? sm[t - off] : 0;
    __syncthreads();
    sm[t] += u;
    __syncthreads();
  }
  int incl = sm[t];
  if (idx < NN) rptmp[a * NN + idx] = incl - v;
  if (t == 1023) btot[a * SBLK + blk] = incl;
}

__global__ __launch_bounds__(256) void scan2_kernel(int* __restrict__ btot) {
  __shared__ int sm[256];
  int t = threadIdx.x;
  for (int a = 0; a < 2; ++a) {
    int v = (t < SBLK) ? btot[a * SBLK + t] : 0;
    sm[t] = v;
    __syncthreads();
    for (int off = 1; off < 256; off <<= 1) {
      int u = (t >= off) ? sm[t - off] : 0;
      __syncthreads();
      sm[t] += u;
      __syncthreads();
    }
    if (t < SBLK) btot[a * SBLK + t] = sm[t] - v;
    __syncthreads();
  }
}

__global__ __launch_bounds__(256) void scan3_kernel(const int* __restrict__ rptmp,
    const int* __restrict__ btot, int* __restrict__ rp, int* __restrict__ cur,
    float* __restrict__ statsA) {
  int gid = blockIdx.x * 256 + threadIdx.x;
  if (gid < 2 * NN) {
    int a = gid / NN, idx = gid - a * NN;
    int v = rptmp[gid] + btot[a * SBLK + (idx >> 10)];
    rp[a * (NN + 1) + idx] = v;
    cur[gid] = v;
    if (idx == 0) rp[a * (NN + 1) + NN] = NE;
  }
  if (gid < 128) statsA[gid] = 0.f;
}

__global__ __launch_bounds__(256) void fill_kernel(const int* __restrict__ src,
    const int* __restrict__ dst, int* __restrict__ cur_in, int* __restrict__ cur_out,
    int* __restrict__ col_in, int* __restrict__ col_out) {
  int stride = gridDim.x * blockDim.x;
  for (int e = blockIdx.x * blockDim.x + threadIdx.x; e < NE; e += stride) {
    int s = src[e], d = dst[e];
    int p = atomicAdd(&cur_in[d], 1);
    col_in[p] = s;
    int q = atomicAdd(&cur_out[s], 1);
    col_out[q] = d;
  }
}

// ---------------- embedding + sel gather ----------------

__global__ __launch_bounds__(256) void embed_kernel(const int* __restrict__ nt,
    const float* __restrict__ emb, float* __restrict__ X) {
  int id = blockIdx.x * 256 + threadIdx.x;
  if (id >= NN * CC) return;
  X[id] = emb[nt[id >> 6] * CC + (id & 63)];
}

__global__ __launch_bounds__(256) void gather_sel_kernel(const float* __restrict__ xsrc,
    const int* __restrict__ idx, float* __restrict__ sel, int coloff) {
  int tid = blockIdx.x * 256 + threadIdx.x;
  if (tid >= KSEL * CC) return;
  int k = tid >> 6, cch = tid & 63;
  sel[k * FULLW + coloff + cch] = xsrc[idx[k] * CC + cch];
}

// ---------------- matmul: Y(bf16) = f(X) @ W ----------------
// W layout [2][64][32]; output col j -> W[j>>5][c][j&31].
// f = BN(relu(.)) from stats (sum,sumsq) if stats!=null else identity.
// Block 0 zeroes stats_zero (the OTHER stats buffer) for the next producer.

__global__ __launch_bounds__(256) void mm_kernel(const float* __restrict__ X,
    __hip_bfloat16* __restrict__ Y, const float* __restrict__ W,
    const float* __restrict__ stats, const float* __restrict__ gamma,
    const float* __restrict__ beta, float* __restrict__ stats_zero) {
  int t = threadIdx.x;
  int lane = t & 63;
  int wid = t >> 6;
  float wreg[CC];
  {
    const float* wb = W + (lane >> 5) * 2048 + (lane & 31);
#pragma unroll
    for (int c2 = 0; c2 < CC; ++c2) wreg[c2] = wb[c2 * 32];
  }
  __shared__ float sc[CC], sh[CC];
  __shared__ __align__(16) float Xs[64][CC];
  if (t < CC) {
    float scale = 1.f, shift = 0.f;
    if (stats) {
      float m = stats[t] * (1.f / NN);
      float v = stats[CC + t] * (1.f / NN) - m * m;
      float is = rsqrtf(v + EPSV);
      scale = gamma[t] * is;
      shift = beta[t] - m * scale;
    }
    sc[t] = scale; sh[t] = shift;
  }
  if (stats_zero && blockIdx.x == 0 && t < 128) stats_zero[t] = 0.f;
  const bool bn = (stats != nullptr);
  for (int row0 = blockIdx.x * 64; row0 < NN; row0 += gridDim.x * 64) {
    int nrows = min(64, NN - row0);
    __syncthreads();
    for (int idx = t; idx < nrows * 16; idx += 256) {
      int r = idx >> 4, cq = idx & 15;
      float4 v = *(const float4*)(X + (size_t)(row0 + r) * CC + cq * 4);
      if (bn) {
        int c0 = cq * 4;
        v.x = fmaxf(v.x, 0.f) * sc[c0]     + sh[c0];
        v.y = fmaxf(v.y, 0.f) * sc[c0 + 1] + sh[c0 + 1];
        v.z = fmaxf(v.z, 0.f) * sc[c0 + 2] + sh[c0 + 2];
        v.w = fmaxf(v.w, 0.f) * sc[c0 + 3] + sh[c0 + 3];
      }
      *(float4*)&Xs[r][cq * 4] = v;
    }
    __syncthreads();
    for (int r = wid; r < nrows; r += 4) {
      const float* xr = &Xs[r][0];
      float a0 = 0.f, a1 = 0.f, a2 = 0.f, a3 = 0.f;
#pragma unroll
      for (int c2 = 0; c2 < CC; c2 += 4) {
        float4 xv = *(const float4*)(xr + c2);
        a0 += xv.x * wreg[c2];
        a1 += xv.y * wreg[c2 + 1];
        a2 += xv.z * wreg[c2 + 2];
        a3 += xv.w * wreg[c2 + 3];
      }
      Y[(size_t)(row0 + r) * CC + lane] = __float2bfloat16((a0 + a1) + (a2 + a3));
    }
  }
}

// ---------------- segment-sum (both directions) + optional skip + BN stats ----------------
// R3-verified structure: channels 0..31 sum in-edges of Y[src][c]; 32..63 out-edges.
// Y is bf16 (64B per half-row gather); 8 independent accumulator chains for MLP.

__global__ __launch_bounds__(256) void seg_kernel(
    const __hip_bfloat16* __restrict__ Y, const float* skip, float* OUT,
    const int* __restrict__ rp_in, const int* __restrict__ col_in,
    const int* __restrict__ rp_out, const int* __restrict__ col_out,
    float* __restrict__ stats_acc) {
  int t = threadIdx.x;
  int c = t & 63;
  int local = t >> 6;
  const int* rp = (c < 32) ? rp_in : rp_out;
  const int* col = (c < 32) ? col_in : col_out;
  float s1 = 0.f, s2 = 0.f;
  for (int i0 = blockIdx.x * 4; i0 < NN; i0 += gridDim.x * 4) {
    int i = i0 + local;
    if (i < NN) {
      int beg = rp[i], end = rp[i + 1];
      float a0 = 0.f, a1 = 0.f, a2 = 0.f, a3 = 0.f;
      float a4 = 0.f, a5 = 0.f, a6 = 0.f, a7 = 0.f;
      int e = beg;
      for (; e + 8 <= end; e += 8) {
        int j0 = col[e], j1 = col[e + 1], j2 = col[e + 2], j3 = col[e + 3];
        int j4 = col[e + 4], j5 = col[e + 5], j6 = col[e + 6], j7 = col[e + 7];
        a0 += __bfloat162float(Y[j0 * CC + c]);
        a1 += __bfloat162float(Y[j1 * CC + c]);
        a2 += __bfloat162float(Y[j2 * CC + c]);
        a3 += __bfloat162float(Y[j3 * CC + c]);
        a4 += __bfloat162float(Y[j4 * CC + c]);
        a5 += __bfloat162float(Y[j5 * CC + c]);
        a6 += __bfloat162float(Y[j6 * CC + c]);
        a7 += __bfloat162float(Y[j7 * CC + c]);
      }
      if (e + 4 <= end) {
        int j0 = col[e], j1 = col[e + 1], j2 = col[e + 2], j3 = col[e + 3];
        a0 += __bfloat162float(Y[j0 * CC + c]);
        a1 += __bfloat162float(Y[j1 * CC + c]);
        a2 += __bfloat162float(Y[j2 * CC + c]);
        a3 += __bfloat162float(Y[j3 * CC + c]);
        e += 4;
      }
      if (e + 2 <= end) {
        int j0 = col[e], j1 = col[e + 1];
        a4 += __bfloat162float(Y[j0 * CC + c]);
        a5 += __bfloat162float(Y[j1 * CC + c]);
        e += 2;
      }
      if (e < end) a6 += __bfloat162float(Y[col[e] * CC + c]);
      float acc = ((a0 + a1) + (a2 + a3)) + ((a4 + a5) + (a6 + a7));
      if (skip) acc += skip[i * CC + c];
      OUT[i * CC + c] = acc;
      float r = fmaxf(acc, 0.f);
      s1 += r; s2 += r * r;
    }
  }
  if (stats_acc) {
    __shared__ float red1[256], red2[256];
    red1[t] = s1; red2[t] = s2;
    __syncthreads();
    if (t < 64) {
      float v1 = red1[t] + red1[t + 64] + red1[t + 128] + red1[t + 192];
      float v2 = red2[t] + red2[t + 64] + red2[t + 128] + red2[t + 192];
      atomicAdd(&stats_acc[t], v1);
      atomicAdd(&stats_acc[CC + t], v2);
    }
  }
}

// ---------------- head ----------------
// 512 blocks: jb in [0,16) x rbg in [0,32). Block: 16 rows x 64 cols.
// Per k0: stage W 64x64 (16KB) + relu'd S 16x64 (4KB) in LDS; wave w does 4 rows.

__global__ __launch_bounds__(256) void hidden_kernel(const float* __restrict__ sel,
    const float* __restrict__ Wh, const float* __restrict__ bh, float* __restrict__ h1) {
  int t = threadIdx.x;
  int lane = t & 63, w = t >> 6;
  int jb = blockIdx.x & 15;
  int rbg = blockIdx.x >> 4;
  int j = jb * 64 + lane;
  int r0 = rbg * 16;
  __shared__ __align__(16) float Ws[64][64];
  __shared__ __align__(16) float Ss[16][64];
  float acc[4] = {0.f, 0.f, 0.f, 0.f};
  for (int k0 = 0; k0 < FULLW; k0 += 64) {
    __syncthreads();
    {
      int col = (t & 15) * 4;
      int kk = t >> 4;
#pragma unroll
      for (int p = 0; p < 4; ++p) {
        float4 v = *(const float4*)(Wh + (size_t)(k0 + kk + p * 16) * HIDD + jb * 64 + col);
        *(float4*)&Ws[kk + p * 16][col] = v;
      }
      float4 v = *(const float4*)(sel + (size_t)(r0 + kk) * FULLW + k0 + col);
      v.x = fmaxf(v.x, 0.f); v.y = fmaxf(v.y, 0.f);
      v.z = fmaxf(v.z, 0.f); v.w = fmaxf(v.w, 0.f);
      *(float4*)&Ss[kk][col] = v;
    }
    __syncthreads();
    float wreg[64];
#pragma unroll
    for (int kk = 0; kk < 64; ++kk) wreg[kk] = Ws[kk][lane];
#pragma unroll
    for (int rr = 0; rr < 4; ++rr) {
      const float4* sr = (const float4*)&Ss[w * 4 + rr][0];
      float a0 = 0.f, a1 = 0.f, a2 = 0.f, a3 = 0.f;
#pragma unroll
      for (int kq = 0; kq < 16; ++kq) {
        float4 sv = sr[kq];
        a0 += sv.x * wreg[kq * 4];
        a1 += sv.y * wreg[kq * 4 + 1];
        a2 += sv.z * wreg[kq * 4 + 2];
        a3 += sv.w * wreg[kq * 4 + 3];
      }
      acc[rr] += (a0 + a1) + (a2 + a3);
    }
  }
#pragma unroll
  for (int rr = 0; rr < 4; ++rr)
    h1[(size_t)(r0 + w * 4 + rr) * HIDD + j] = acc[rr] + bh[j];
}

__global__ __launch_bounds__(256) void out_kernel(const float* __restrict__ h1,
    const float* __restrict__ ow, const float* __restrict__ ob, float* __restrict__ logits) {
  int k = blockIdx.x * 4 + (threadIdx.x >> 6);
  int lane = threadIdx.x & 63;
  if (k >= KSEL) return;
  float a = 0.f;
  for (int j = lane; j < HIDD; j += 64) {
    float v = h1[k * HIDD + j];
    a += fmaxf(v, 0.f) * ow[j];
  }
  for (int off = 32; off; off >>= 1) a += __shfl_down(a, off, 64);
  if (lane == 0) logits[k] = a + ob[0];
}

__global__ __launch_bounds__(512) void softmax_kernel(const float* __restrict__ logits,
    float* __restrict__ out) {
  int t = threadIdx.x;
  float v = logits[t];
  __shared__ float red[512];
  red[t] = v;
  __syncthreads();
  for (int s = 256; s; s >>= 1) { if (t < s) red[t] = fmaxf(red[t], red[t + s]); __syncthreads(); }
  float mx = red[0];
  __syncthreads();
  float e = expf(v - mx);
  red[t] = e;
  __syncthreads();
  for (int s = 256; s; s >>= 1) { if (t < s) red[t] += red[t + s]; __syncthreads(); }
  out[t] = e / red[0];
}

// ---------------- launch ----------------

extern "C" void kernel_launch(void* const* d_in, const int* in_sizes, int n_in,
                              void* d_out, int out_size, void* d_ws, size_t ws_size,
                              hipStream_t stream) {
  const int* node_types = (const int*)d_in[0];
  const int* edge_index = (const int*)d_in[1];
  const int* indices = (const int*)d_in[2];
  const float* emb = (const float*)d_in[3];
  const float* conv0_w = (const float*)d_in[4];
  const float* bn_g = (const float*)d_in[5];
  const float* bn_b = (const float*)d_in[6];
  const float* res_w = (const float*)d_in[7];
  const float* hw = (const float*)d_in[8];
  const float* hb = (const float*)d_in[9];
  const float* ow = (const float*)d_in[10];
  const float* ob = (const float*)d_in[11];
  float* out = (float*)d_out;
  const int* src = edge_index;
  const int* dst = edge_index + NE;

  char* p = (char*)d_ws;
  size_t off = 0;
  auto alloc = [&](size_t bytes) -> void* {
    void* q = p + off;
    off += (bytes + 255) & ~(size_t)255;
    return q;
  };
  int* cnt = (int*)alloc(2 * NN * sizeof(int));        // cnt_in | cnt_out
  int* rptmp = (int*)alloc(2 * NN * sizeof(int));
  int* btot = (int*)alloc(2 * SBLK * sizeof(int));
  int* rp = (int*)alloc(2 * (NN + 1) * sizeof(int));   // rp_in | rp_out
  int* cur = (int*)alloc(2 * NN * sizeof(int));
  int* col_in = (int*)alloc((size_t)NE * sizeof(int));
  int* col_out = (int*)alloc((size_t)NE * sizeof(int));
  float* X = (float*)alloc((size_t)NN * CC * 4);
  float* H = (float*)alloc((size_t)NN * CC * 4);
  __hip_bfloat16* Y = (__hip_bfloat16*)alloc((size_t)NN * CC * 2);
  float* statsA = (float*)alloc(128 * 4);
  float* statsB = (float*)alloc(128 * 4);
  float* sel = (float*)alloc((size_t)KSEL * FULLW * 4);
  float* h1 = (float*)alloc((size_t)KSEL * HIDD * 4);
  float* logits = (float*)alloc(KSEL * 4);
  (void)ws_size; (void)in_sizes; (void)n_in; (void)out_size;

  int* cnt_in = cnt;  int* cnt_out = cnt + NN;
  int* rp_in = rp;    int* rp_out = rp + NN + 1;
  int* cur_in = cur;  int* cur_out = cur + NN;

  hipMemsetAsync(cnt, 0, 2 * NN * sizeof(int), stream);
  hipLaunchKernelGGL(hist_kernel, dim3(1024), dim3(256), 0, stream, src, dst, cnt_in, cnt_out);
  hipLaunchKernelGGL(scan1_kernel, dim3(2 * SBLK), dim3(1024), 0, stream, cnt, rptmp, btot);
  hipLaunchKernelGGL(scan2_kernel, dim3(1), dim3(256), 0, stream, btot);
  hipLaunchKernelGGL(scan3_kernel, dim3((2 * NN + 255) / 256), dim3(256), 0, stream,
                     rptmp, btot, rp, cur, statsA);
  hipLaunchKernelGGL(fill_kernel, dim3(1024), dim3(256), 0, stream, src, dst,
                     cur_in, cur_out, col_in, col_out);

  hipLaunchKernelGGL(embed_kernel, dim3((NN * CC + 255) / 256), dim3(256), 0, stream,
                     node_types, emb, X);
  hipLaunchKernelGGL(gather_sel_kernel, dim3(KSEL * CC / 256), dim3(256), 0, stream,
                     X, indices, sel, 0);

  // conv0 (no BN); accumulate relu stats of its output into statsA
  hipLaunchKernelGGL(mm_kernel, dim3(782), dim3(256), 0, stream, X, Y, conv0_w,
                     (const float*)nullptr, (const float*)nullptr, (const float*)nullptr,
                     (float*)nullptr);
  hipLaunchKernelGGL(seg_kernel, dim3(2048), dim3(256), 0, stream, Y, (const float*)nullptr, X,
                     rp_in, col_in, rp_out, col_out, statsA);
  hipLaunchKernelGGL(gather_sel_kernel, dim3(KSEL * CC / 256), dim3(256), 0, stream,
                     X, indices, sel, CC);

  for (int l = 0; l < LL; ++l) {
    const float* w1 = res_w + (size_t)(l * 2 + 0) * 4096;
    const float* w2 = res_w + (size_t)(l * 2 + 1) * 4096;
    const float* g1 = bn_g + (l * 2 + 0) * CC;
    const float* b1 = bn_b + (l * 2 + 0) * CC;
    const float* g2 = bn_g + (l * 2 + 1) * CC;
    const float* b2 = bn_b + (l * 2 + 1) * CC;
    hipLaunchKernelGGL(mm_kernel, dim3(782), dim3(256), 0, stream, X, Y, w1, statsA, g1, b1, statsB);
    hipLaunchKernelGGL(seg_kernel, dim3(2048), dim3(256), 0, stream, Y, (const float*)nullptr, H,
                       rp_in, col_in, rp_out, col_out, statsB);
    hipLaunchKernelGGL(mm_kernel, dim3(782), dim3(256), 0, stream, H, Y, w2, statsB, g2, b2, statsA);
    hipLaunchKernelGGL(seg_kernel, dim3(2048), dim3(256), 0, stream, Y, X, X,
                       rp_in, col_in, rp_out, col_out, statsA);
    hipLaunchKernelGGL(gather_sel_kernel, dim3(KSEL * CC / 256), dim3(256), 0, stream,
                       X, indices, sel, 2 * CC + l * CC);
  }

  hipLaunchKernelGGL(hidden_kernel, dim3(512), dim3(256), 0, stream, sel, hw, hb, h1);
  hipLaunchKernelGGL(out_kernel, dim3(KSEL / 4), dim3(256), 0, stream, h1, ow, ob, logits);
  hipLaunchKernelGGL(softmax_kernel, dim3(1), dim3(512), 0, stream, logits, out);
}